// Round 9
// baseline (295.383 us; speedup 1.0000x reference)
//
#include <hip/hip_runtime.h>
#include <hip/hip_bf16.h>

#define NB 8192   // batch
#define ND 1024   // feature dim

typedef __bf16 bf16x8 __attribute__((ext_vector_type(8)));
typedef int    i32x4  __attribute__((ext_vector_type(4)));
typedef float  f32x4  __attribute__((ext_vector_type(4)));

// async global -> LDS, 16B per lane. LDS dest = wave-uniform base + lane*16.
__device__ inline void gload_lds16(const void* g, void* l) {
    __builtin_amdgcn_global_load_lds(
        (const __attribute__((address_space(1))) unsigned int*)g,
        (__attribute__((address_space(3))) unsigned int*)l,
        16, 0, 0);
}

// asm 16B global->VGPR load; counted manually via vmcnt (compiler unaware).
__device__ inline void bload(const unsigned short* p, i32x4& d) {
    asm volatile("global_load_dwordx4 %0, %1, off"
                 : "=v"(d) : "v"(p) : "memory");
}

__device__ inline unsigned short f2bf(float x) {
    unsigned int u = __float_as_uint(x);
    return (unsigned short)((u + 0x7fffu + ((u >> 16) & 1u)) >> 16);
}

#define BARRIER() asm volatile("s_barrier" ::: "memory")
#define VMCNT6()  asm volatile("s_waitcnt vmcnt(6)" ::: "memory")
#define VMCNT0()  asm volatile("s_waitcnt vmcnt(0)" ::: "memory")
#define LGKM0()   asm volatile("s_waitcnt lgkmcnt(0)" ::: "memory")

// ---------------------------------------------------------------------------
// Kernel 1: per-row L2 norms + conversion. A -> row-major bf16 (wa, for LDS
// staging). B -> FRAGMENT-PACKED bf16 (wb2): short index =
//   (col>>4)*16384 + (k>>3)*128 + (col&15)*8 + (k&7)
// so a wave's MFMA B-frag is one coalesced dwordx4 per lane from global.
// ---------------------------------------------------------------------------
__global__ __launch_bounds__(256) void prep_kernel(
    const float* __restrict__ A, const float* __restrict__ Bm,
    unsigned short* __restrict__ wa, unsigned short* __restrict__ wb2,
    float* __restrict__ na, float* __restrict__ nb)
{
    int b = blockIdx.x;
    int wid = threadIdx.x >> 6, lane = threadIdx.x & 63;
    bool isA = (b < 2048);
    int row = (isA ? b : b - 2048) * 4 + wid;
    const float* rp = (isA ? A : Bm) + (size_t)row * ND;

    float ss = 0.f;
#pragma unroll
    for (int t = 0; t < 4; ++t) {
        int c = lane * 4 + t * 256;
        float4 v = *reinterpret_cast<const float4*>(rp + c);
        ss += v.x * v.x + v.y * v.y + v.z * v.z + v.w * v.w;
        ushort4 u;
        u.x = f2bf(v.x); u.y = f2bf(v.y); u.z = f2bf(v.z); u.w = f2bf(v.w);
        if (isA) {
            *reinterpret_cast<ushort4*>(wa + (size_t)row * ND + c) = u;
        } else {
            size_t idx = (size_t)(row >> 4) * 16384 + (c >> 3) * 128
                       + (row & 15) * 8 + (c & 7);
            *reinterpret_cast<ushort4*>(wb2 + idx) = u;
        }
    }
#pragma unroll
    for (int off = 32; off; off >>= 1) ss += __shfl_xor(ss, off);
    if (lane == 0) (isA ? na : nb)[row] = sqrtf(ss);
}

// ---------------------------------------------------------------------------
// Kernel 2: label histogram (integer LDS atomics -> deterministic).
// ---------------------------------------------------------------------------
__global__ __launch_bounds__(256) void hist_kernel(
    const int* __restrict__ labels, int* __restrict__ hist)
{
    __shared__ int h[128];
    int tid = threadIdx.x;
    if (tid < 128) h[tid] = 0;
    __syncthreads();
    for (int i = tid; i < NB; i += 256) atomicAdd(&h[labels[i]], 1);
    __syncthreads();
    if (tid < 128) hist[tid] = h[tid];
}

// ---------------------------------------------------------------------------
// Kernel 3: 128x128-tile bf16 GEMM. A via tri-buffered LDS (3 x 8 KiB only),
// B DIRECT global->reg from fragment-packed wb2 (never touches LDS):
// K-loop LDS traffic halves (24 KB/block-iter), ds_reads 4/wave/iter.
// Per iter: STAGE A(t+2) [2 gl_lds] ; BLOAD B(t+1) [4 asm dwordx4] ;
// ds_read af ; vmcnt(6) [in-order retirement => B(t) AND A(t+1) complete] ;
// sched_barrier(0) [rule 18: keep MFMA below the wait] ; 16 MFMA ;
// lgkmcnt(0) [RACE FIX: ds_reads complete before buffer handoff] ; s_barrier.
// T2 granule swizzle on A (R8-verified, 0 conflicts). XCD-row mapping.
// Epilogue: scale to cos, write C, fused per-row loss partials.
// ---------------------------------------------------------------------------
__global__ __launch_bounds__(256) void gemm_cos(
    const unsigned short* __restrict__ wa, const unsigned short* __restrict__ wb2,
    const float* __restrict__ na, const float* __restrict__ nb,
    const int* __restrict__ labels,
    float* __restrict__ C, float* __restrict__ pe, float* __restrict__ pm)
{
    // 3 bufs x [A 128x32] bf16 = 3 x 4096 shorts = 24 KiB
    __shared__ unsigned short lds[12288];

    const int bid = blockIdx.x;                 // 4096 blocks
    const int tm  = (bid & 7) * 8 + ((bid >> 3) & 7);   // XCD owns 8 tm rows
    const int tn  = bid >> 6;                            // B streams

    const int tid  = threadIdx.x;
    const int lane = tid & 63;
    const int wid  = tid >> 6;
    const int wr   = wid >> 1, wc = wid & 1;
    const int l15  = lane & 15, lg = lane >> 4;

    const int m0 = tm * 128, n0 = tn * 128;

    // A staging: thread -> row tid>>2 (0..63 per call), granule tid&3; global
    // granule pre-swizzled: (tid&3) ^ ((row>>1)&3).
    const int srow = tid >> 2;
    const int sg   = (tid & 3) ^ ((tid >> 3) & 3);
    const unsigned short* pA0 = wa + (size_t)(m0 + srow) * ND + sg * 8;
    const unsigned short* pA1 = pA0 + 64 * ND;
    const int stW = wid * 512;   // wave-uniform LDS dest base per 64-row call

    // A fragment reads: kg = (lg ^ ((row>>1)&3))*8; row bits from l15 only.
    const int kg  = (lg ^ ((lane >> 1) & 3)) * 8;
    const int rdA = wr * 2048 + l15 * 32 + kg;            // + m*512

    // B fragment base (shorts): per (n, t): + n*16384 + t*512
    const unsigned short* qB = wb2 + (size_t)tn * 131072 + wc * 65536
                             + lg * 128 + l15 * 8;

    f32x4 acc[4][4];
#pragma unroll
    for (int i = 0; i < 4; ++i)
#pragma unroll
        for (int j = 0; j < 4; ++j) acc[i][j] = (f32x4){0.f, 0.f, 0.f, 0.f};

    i32x4 breg[2][4];

#define STAGE_A(t, BUF) do { \
    gload_lds16(pA0 + (t) * 32, &lds[(BUF) + stW]); \
    gload_lds16(pA1 + (t) * 32, &lds[(BUF) + 2048 + stW]); } while (0)

#define BLOAD(t, P) do { _Pragma("unroll") \
    for (int n_ = 0; n_ < 4; ++n_) \
        bload(qB + (t) * 512 + n_ * 16384, breg[P][n_]); } while (0)

    // Prologue: A tiles 0,1 staged; B tile 0 loaded.
    STAGE_A(0, 0);
    STAGE_A(1, 4096);
    BLOAD(0, 0);
    VMCNT6();           // A(0) complete (A(1)+B(0)=6 still in flight)
    BARRIER();

#pragma unroll
    for (int t = 0; t < 32; ++t) {
        const int cb  = (t % 3) * 4096;
        const int nb2 = ((t + 2) % 3) * 4096;
        const int cp  = t & 1, np = cp ^ 1;
        if (t < 30) STAGE_A(t + 2, nb2);      // 2 vm
        if (t < 31) BLOAD(t + 1, np);         // 4 vm
        bf16x8 af[4];
#pragma unroll
        for (int m_ = 0; m_ < 4; ++m_)
            af[m_] = *reinterpret_cast<const bf16x8*>(&lds[cb + rdA + m_ * 512]);
        if (t < 31) VMCNT6();                 // B(t) + A(t+1) complete
        else        VMCNT0();
        __builtin_amdgcn_sched_barrier(0);    // keep MFMA below the wait
#pragma unroll
        for (int m_ = 0; m_ < 4; ++m_)
#pragma unroll
            for (int n_ = 0; n_ < 4; ++n_)
                acc[m_][n_] = __builtin_amdgcn_mfma_f32_16x16x32_bf16(
                    af[m_], __builtin_bit_cast(bf16x8, breg[cp][n_]),
                    acc[m_][n_], 0, 0, 0);
        LGKM0();                              // RACE FIX: ds_reads done
        BARRIER();
    }

#undef BLOAD
#undef STAGE_A

    // ---------------- epilogue: cos write + fused loss partials ------------
    __syncthreads();                 // LDS reusable
    float* pl = reinterpret_cast<float*>(lds);   // [128 rows][2 wc][2] floats

    float nbv[4]; int labc[4];
#pragma unroll
    for (int n = 0; n < 4; ++n) {
        int c = n0 + wc * 64 + n * 16 + l15;
        nbv[n] = nb[c]; labc[n] = labels[c];
    }

#pragma unroll
    for (int m = 0; m < 4; ++m) {
#pragma unroll
        for (int jj = 0; jj < 4; ++jj) {
            int rl = wr * 64 + m * 16 + lg * 4 + jj;   // 0..127
            int r  = m0 + rl;
            float nav = na[r]; int labr = labels[r];
            float es = 0.f, ms = 0.f;
#pragma unroll
            for (int n = 0; n < 4; ++n) {
                int c = n0 + wc * 64 + n * 16 + l15;
                float v = acc[m][n][jj] / fmaxf(nav * nbv[n], 1e-8f);
                C[(size_t)r * NB + c] = v;
                es += __expf(v);
                ms += (labc[n] == labr) ? v : 0.f;
            }
#pragma unroll
            for (int off = 1; off < 16; off <<= 1) {
                es += __shfl_xor(es, off);
                ms += __shfl_xor(ms, off);
            }
            if (l15 == 0) {
                int o = rl * 4 + wc * 2;
                pl[o] = es; pl[o + 1] = ms;
            }
        }
    }
    __syncthreads();
    if (tid < 128) {
        float es = pl[tid * 4]     + pl[tid * 4 + 2];
        float ms = pl[tid * 4 + 1] + pl[tid * 4 + 3];
        pe[tn * NB + m0 + tid] = es;
        pm[tn * NB + m0 + tid] = ms;
    }
}

// ---------------------------------------------------------------------------
// Kernel 4: reduce 64 column-tile partials -> per-row loss.
// ---------------------------------------------------------------------------
__global__ __launch_bounds__(256) void loss_final(
    const float* __restrict__ pe, const float* __restrict__ pm,
    const int* __restrict__ labels, const int* __restrict__ hist,
    float* __restrict__ per_row)
{
    int row = blockIdx.x * 256 + threadIdx.x;
    float es = 0.f, ms = 0.f;
#pragma unroll
    for (int t = 0; t < 64; ++t) {
        es += pe[t * NB + row];
        ms += pm[t * NB + row];
    }
    per_row[row] = logf(es) - ms / (float)hist[labels[row]];
}

// ---------------------------------------------------------------------------
// Kernel 5: deterministic mean of per_row -> out[0]
// ---------------------------------------------------------------------------
__global__ __launch_bounds__(256) void finalize(
    const float* __restrict__ per_row, float* __restrict__ out)
{
    __shared__ float sm[256];
    float s = 0.f;
    for (int i = threadIdx.x; i < NB; i += 256) s += per_row[i];
    sm[threadIdx.x] = s;
    __syncthreads();
    for (int k = 128; k; k >>= 1) {
        if (threadIdx.x < k) sm[threadIdx.x] += sm[threadIdx.x + k];
        __syncthreads();
    }
    if (threadIdx.x == 0) out[0] = sm[0] * (1.0f / (float)NB);
}

extern "C" void kernel_launch(void* const* d_in, const int* in_sizes, int n_in,
                              void* d_out, int out_size, void* d_ws, size_t ws_size,
                              hipStream_t stream) {
    const int*   labels = (const int*)d_in[0];
    const float* A      = (const float*)d_in[1];
    const float* Bm     = (const float*)d_in[2];
    float* out = (float*)d_out;

    // workspace layout (~38.2 MB)
    char* ws = (char*)d_ws;
    unsigned short* wa  = (unsigned short*)(ws);                    // 16 MB
    unsigned short* wb2 = (unsigned short*)(ws + 16777216);         // 16 MB
    float* na      = (float*)(ws + 33554432);                       // 32 KB
    float* nb      = (float*)(ws + 33554432 + 32768);               // 32 KB
    float* per_row = (float*)(ws + 33554432 + 65536);               // 32 KB
    int*   hist    = (int*)  (ws + 33554432 + 98304);               // 512 B
    float* pe      = (float*)(ws + 33554432 + 131072);              // 2 MB
    float* pm      = (float*)(ws + 33554432 + 131072 + 2097152);    // 2 MB

    float* cosm = out + 1;   // out[0]=loss, out[1..] = cos_score row-major

    prep_kernel<<<4096, 256, 0, stream>>>(A, Bm, wa, wb2, na, nb);
    hist_kernel<<<1,    256, 0, stream>>>(labels, hist);
    gemm_cos   <<<4096, 256, 0, stream>>>(wa, wb2, na, nb, labels, cosm, pe, pm);
    loss_final <<<32,   256, 0, stream>>>(pe, pm, labels, hist, per_row);
    finalize   <<<1,    256, 0, stream>>>(per_row, out);
}

// Round 10
// 274.456 us; speedup vs baseline: 1.0763x; 1.0763x over previous
//
#include <hip/hip_runtime.h>
#include <hip/hip_bf16.h>

#define NB 8192   // batch
#define ND 1024   // feature dim

typedef __bf16 bf16x8 __attribute__((ext_vector_type(8)));
typedef float  f32x4  __attribute__((ext_vector_type(4)));

// async global -> LDS, 16B per lane. LDS dest = wave-uniform base + lane*16.
__device__ inline void gload_lds16(const void* g, void* l) {
    __builtin_amdgcn_global_load_lds(
        (const __attribute__((address_space(1))) unsigned int*)g,
        (__attribute__((address_space(3))) unsigned int*)l,
        16, 0, 0);
}

__device__ inline unsigned short f2bf(float x) {
    unsigned int u = __float_as_uint(x);
    return (unsigned short)((u + 0x7fffu + ((u >> 16) & 1u)) >> 16);
}

#define BARRIER() asm volatile("s_barrier" ::: "memory")
#define VMCNT0()  asm volatile("s_waitcnt vmcnt(0)" ::: "memory")
#define LGKM0()   asm volatile("s_waitcnt lgkmcnt(0)" ::: "memory")

// ---------------------------------------------------------------------------
// Kernel 1: per-row L2 norms of A and B + bf16 conversion into workspace.
// ---------------------------------------------------------------------------
__global__ __launch_bounds__(256) void prep_kernel(
    const float* __restrict__ A, const float* __restrict__ Bm,
    unsigned short* __restrict__ wa, unsigned short* __restrict__ wb,
    float* __restrict__ na, float* __restrict__ nb)
{
    int b = blockIdx.x;
    int wid = threadIdx.x >> 6, lane = threadIdx.x & 63;
    const float* src; unsigned short* dst; float* nrm; int row;
    if (b < 2048) { src = A;  dst = wa; nrm = na; row = b * 4 + wid; }
    else          { src = Bm; dst = wb; nrm = nb; row = (b - 2048) * 4 + wid; }

    const float*    rp = src + (size_t)row * ND;
    unsigned short* wp = dst + (size_t)row * ND;

    float ss = 0.f;
#pragma unroll
    for (int t = 0; t < 4; ++t) {
        int c = lane * 4 + t * 256;
        float4 v = *reinterpret_cast<const float4*>(rp + c);
        ss += v.x * v.x + v.y * v.y + v.z * v.z + v.w * v.w;
        ushort4 u;
        u.x = f2bf(v.x); u.y = f2bf(v.y); u.z = f2bf(v.z); u.w = f2bf(v.w);
        *reinterpret_cast<ushort4*>(wp + c) = u;
    }
#pragma unroll
    for (int off = 32; off; off >>= 1) ss += __shfl_xor(ss, off);
    if (lane == 0) nrm[row] = sqrtf(ss);
}

// ---------------------------------------------------------------------------
// Kernel 2: label histogram (integer LDS atomics -> deterministic).
// ---------------------------------------------------------------------------
__global__ __launch_bounds__(256) void hist_kernel(
    const int* __restrict__ labels, int* __restrict__ hist)
{
    __shared__ int h[128];
    int tid = threadIdx.x;
    if (tid < 128) h[tid] = 0;
    __syncthreads();
    for (int i = tid; i < NB; i += 256) atomicAdd(&h[labels[i]], 1);
    __syncthreads();
    if (tid < 128) hist[tid] = h[tid];
}

// ---------------------------------------------------------------------------
// Kernel 3: 128x128-tile bf16 GEMM, BK=64, double-buffered LDS (2 x 32 KiB)
// -> 2 blocks/CU co-resident. 16 K-iters (half of R8) so per-iter sync cost
// amortizes 2x. Per iter: STAGE(t+1) 8 gloads (issued FIRST) -> 16
// ds_read_b128 -> 32 MFMA -> sched_barrier -> vmcnt(0) (covered by ~700 cyc
// of reads+MFMA; full drain = no tail miscount possible) -> lgkmcnt(0)
// (no ds_read crosses the barrier) -> s_barrier.
// Rows are 64 shorts (128 B): read granule (ks*4+lg) ^ (row&7) (ks=1 is ^32),
// staging pre-swizzles the global source with the same involution.
// Epilogue: scale to cos, write C, fused per-row loss partials.
// ---------------------------------------------------------------------------
__global__ __launch_bounds__(256) void gemm_cos(
    const unsigned short* __restrict__ wa, const unsigned short* __restrict__ wb,
    const float* __restrict__ na, const float* __restrict__ nb,
    const int* __restrict__ labels,
    float* __restrict__ C, float* __restrict__ pe, float* __restrict__ pm)
{
    // 2 bufs x [A 128x64 | B 128x64] bf16 = 2 x 16384 shorts = 64 KiB
    __shared__ unsigned short lds[32768];

    const int bid = blockIdx.x;                 // 4096 blocks
    const int tm  = (bid & 7) * 8 + ((bid >> 3) & 7);   // XCD owns 8 tm rows
    const int tn  = bid >> 6;                            // B streams

    const int tid  = threadIdx.x;
    const int lane = tid & 63;
    const int wid  = tid >> 6;
    const int wr   = wid >> 1, wc = wid & 1;
    const int l15  = lane & 15, lg = lane >> 4;

    const int m0 = tm * 128, n0 = tn * 128;

    // Staging: thread -> row tid>>3 (0..31 per gload), 16B granule tid&7;
    // global granule pre-swizzled: (tid&7) ^ (row&7)  (row&7 invariant under
    // the +32-row chunk steps).
    const int srow = tid >> 3;
    const int sgr  = (tid & 7) ^ (srow & 7);
    const unsigned short* pA = wa + (size_t)(m0 + srow) * ND + sgr * 8;
    const unsigned short* pB = wb + (size_t)(n0 + srow) * ND + sgr * 8;
    const int stW = wid * 512;    // wave-uniform dest base (shorts) per chunk

    // Fragment reads (shorts): addr = row*64 + ((ks*4+lg)^(row&7))*8
    //   = base + m(or n)*1024, with ks=1 applied as ^32 (4+lg = 4^lg, lg<4).
    const int kg = (lg ^ (l15 & 7)) * 8;
    const int bA = (wr * 64 + l15) * 64 + kg;           // + m*1024 (16 rows)
    const int bB = 8192 + (wc * 64 + l15) * 64 + kg;    // + n*1024

    f32x4 acc[4][4];
#pragma unroll
    for (int i = 0; i < 4; ++i)
#pragma unroll
        for (int j = 0; j < 4; ++j) acc[i][j] = (f32x4){0.f, 0.f, 0.f, 0.f};

#define STAGE(t, BUF) do { \
    _Pragma("unroll") \
    for (int c_ = 0; c_ < 4; ++c_) { \
        gload_lds16(pA + (size_t)c_ * 32 * ND + (t) * 64, \
                    &lds[(BUF) + c_ * 2048 + stW]); \
        gload_lds16(pB + (size_t)c_ * 32 * ND + (t) * 64, \
                    &lds[(BUF) + 8192 + c_ * 2048 + stW]); \
    } } while (0)

#define COMPUTE(BUF) do { \
    _Pragma("unroll") \
    for (int ks_ = 0; ks_ < 2; ++ks_) { \
        const int kx = ks_ * 32; \
        bf16x8 bq[4], af[4]; \
        _Pragma("unroll") \
        for (int n_ = 0; n_ < 4; ++n_) \
            bq[n_] = *reinterpret_cast<const bf16x8*>( \
                &lds[(BUF) + ((bB + n_ * 1024) ^ kx)]); \
        _Pragma("unroll") \
        for (int m_ = 0; m_ < 4; ++m_) \
            af[m_] = *reinterpret_cast<const bf16x8*>( \
                &lds[(BUF) + ((bA + m_ * 1024) ^ kx)]); \
        _Pragma("unroll") \
        for (int m_ = 0; m_ < 4; ++m_) \
            _Pragma("unroll") \
            for (int n_ = 0; n_ < 4; ++n_) \
                acc[m_][n_] = __builtin_amdgcn_mfma_f32_16x16x32_bf16( \
                    af[m_], bq[n_], acc[m_][n_], 0, 0, 0); \
    } } while (0)

    // Prologue: stage tile 0 into buf0.
    STAGE(0, 0);
    VMCNT0();
    BARRIER();

#pragma unroll
    for (int t = 0; t < 16; ++t) {
        const int cb = (t & 1) * 16384;
        if (t < 15) STAGE(t + 1, cb ^ 16384);   // issue-early
        COMPUTE(cb);                            // ~700+ cyc of cover
        __builtin_amdgcn_sched_barrier(0);      // nothing crosses the waits
        VMCNT0();                               // stage(t+1) landed
        LGKM0();                                // no ds_read crosses barrier
        BARRIER();
    }

#undef COMPUTE
#undef STAGE

    // ---------------- epilogue: cos write + fused loss partials ------------
    __syncthreads();                 // LDS reusable
    float* pl = reinterpret_cast<float*>(lds);   // [128 rows][2 wc][2] floats

    float nbv[4]; int labc[4];
#pragma unroll
    for (int n = 0; n < 4; ++n) {
        int c = n0 + wc * 64 + n * 16 + l15;
        nbv[n] = nb[c]; labc[n] = labels[c];
    }

#pragma unroll
    for (int m = 0; m < 4; ++m) {
#pragma unroll
        for (int jj = 0; jj < 4; ++jj) {
            int rl = wr * 64 + m * 16 + lg * 4 + jj;   // 0..127
            int r  = m0 + rl;
            float nav = na[r]; int labr = labels[r];
            float es = 0.f, ms = 0.f;
#pragma unroll
            for (int n = 0; n < 4; ++n) {
                int c = n0 + wc * 64 + n * 16 + l15;
                float v = acc[m][n][jj] / fmaxf(nav * nbv[n], 1e-8f);
                C[(size_t)r * NB + c] = v;
                es += __expf(v);
                ms += (labc[n] == labr) ? v : 0.f;
            }
#pragma unroll
            for (int off = 1; off < 16; off <<= 1) {
                es += __shfl_xor(es, off);
                ms += __shfl_xor(ms, off);
            }
            if (l15 == 0) {
                int o = rl * 4 + wc * 2;
                pl[o] = es; pl[o + 1] = ms;
            }
        }
    }
    __syncthreads();
    if (tid < 128) {
        float es = pl[tid * 4]     + pl[tid * 4 + 2];
        float ms = pl[tid * 4 + 1] + pl[tid * 4 + 3];
        pe[tn * NB + m0 + tid] = es;
        pm[tn * NB + m0 + tid] = ms;
    }
}

// ---------------------------------------------------------------------------
// Kernel 4: reduce 64 column-tile partials -> per-row loss.
// ---------------------------------------------------------------------------
__global__ __launch_bounds__(256) void loss_final(
    const float* __restrict__ pe, const float* __restrict__ pm,
    const int* __restrict__ labels, const int* __restrict__ hist,
    float* __restrict__ per_row)
{
    int row = blockIdx.x * 256 + threadIdx.x;
    float es = 0.f, ms = 0.f;
#pragma unroll
    for (int t = 0; t < 64; ++t) {
        es += pe[t * NB + row];
        ms += pm[t * NB + row];
    }
    per_row[row] = logf(es) - ms / (float)hist[labels[row]];
}

// ---------------------------------------------------------------------------
// Kernel 5: deterministic mean of per_row -> out[0]
// ---------------------------------------------------------------------------
__global__ __launch_bounds__(256) void finalize(
    const float* __restrict__ per_row, float* __restrict__ out)
{
    __shared__ float sm[256];
    float s = 0.f;
    for (int i = threadIdx.x; i < NB; i += 256) s += per_row[i];
    sm[threadIdx.x] = s;
    __syncthreads();
    for (int k = 128; k; k >>= 1) {
        if (threadIdx.x < k) sm[threadIdx.x] += sm[threadIdx.x + k];
        __syncthreads();
    }
    if (threadIdx.x == 0) out[0] = sm[0] * (1.0f / (float)NB);
}

extern "C" void kernel_launch(void* const* d_in, const int* in_sizes, int n_in,
                              void* d_out, int out_size, void* d_ws, size_t ws_size,
                              hipStream_t stream) {
    const int*   labels = (const int*)d_in[0];
    const float* A      = (const float*)d_in[1];
    const float* Bm     = (const float*)d_in[2];
    float* out = (float*)d_out;

    // workspace layout (~38.2 MB)
    char* ws = (char*)d_ws;
    unsigned short* wa = (unsigned short*)(ws);                     // 16 MB
    unsigned short* wb = (unsigned short*)(ws + 16777216);          // 16 MB
    float* na      = (float*)(ws + 33554432);                       // 32 KB
    float* nb      = (float*)(ws + 33554432 + 32768);               // 32 KB
    float* per_row = (float*)(ws + 33554432 + 65536);               // 32 KB
    int*   hist    = (int*)  (ws + 33554432 + 98304);               // 512 B
    float* pe      = (float*)(ws + 33554432 + 131072);              // 2 MB
    float* pm      = (float*)(ws + 33554432 + 131072 + 2097152);    // 2 MB

    float* cosm = out + 1;   // out[0]=loss, out[1..] = cos_score row-major

    prep_kernel<<<4096, 256, 0, stream>>>(A, Bm, wa, wb, na, nb);
    hist_kernel<<<1,    256, 0, stream>>>(labels, hist);
    gemm_cos   <<<4096, 256, 0, stream>>>(wa, wb, na, nb, labels, cosm, pe, pm);
    loss_final <<<32,   256, 0, stream>>>(pe, pm, labels, hist, per_row);
    finalize   <<<1,    256, 0, stream>>>(per_row, out);
}